// Round 7
// baseline (1616.075 us; speedup 1.0000x reference)
//
#include <hip/hip_runtime.h>
#include <hip/hip_bf16.h>
#include <stdint.h>

// Problem constants (B=2, NV=25000, C=32, NR=3, ND=16, F=64)
#define NVERT 25000      // vertices per batch
#define NGRP5 10000      // groups of 5 vertices (50000/5, exact)

typedef __bf16  bf16x8 __attribute__((ext_vector_type(8)));
typedef float   f32x4  __attribute__((ext_vector_type(4)));

// ---- 16x16x32 design: f-quarter (n=16) B-pack, 49 K-chunks (48 conv + 1 center)
#define NKC     49
#define BPACK_Q_USHORT (NKC*512)        // ushorts per f-quarter pack (25088)
#define LDS_B16 (NKC*1024)              // 50176 B of B-fragments in LDS
#define SLOTV   1024                    // per-vert per-r patch: 16 rows x 64 B
#define WPATCH  (2*5*SLOTV + 320)       // 2 parity slots x 5 verts + center rows = 10560 B
#define LDS_TOT (LDS_B16 + 8*WPATCH)    // 134656 <= 163840; 1 block/CU, 2 waves/SIMD

__device__ __forceinline__ uint2 pack4(float4 v) {
  union { __hip_bfloat162 h; unsigned u; } a, b;
  a.h = __float22bfloat162_rn(float2{v.x, v.y});
  b.h = __float22bfloat162_rn(float2{v.z, v.w});
  return uint2{a.u, b.u};
}

__device__ __forceinline__ unsigned short f2bf(float f) {
  unsigned int u = __float_as_uint(f);
  u += 0x7FFFu + ((u >> 16) & 1u);   // round-to-nearest-even
  return (unsigned short)(u >> 16);
}

// lane-rotate within 16-lane rows (row_ror:15): dst[i] = src[(i+1)&15] — harness-verified
// in-place form (R3/R5 passed): single v_mov_b32_dpp per dword.
__device__ __forceinline__ bf16x8 rot16(bf16x8 x) {
  union { bf16x8 v; int i[4]; } u;
  u.v = x;
#pragma unroll
  for (int k = 0; k < 4; ++k)
    u.i[k] = __builtin_amdgcn_update_dpp(u.i[k], u.i[k], 0x12F, 0xF, 0xF, false);
  return u.v;
}

// Pack kernel (3,16,32,64) + center_kernel (32,64) into 16x16x32 MFMA B-fragment order.
// Layout: bpack[fq(4)][kc(49)][lane(64)][i(8)] ushort.
// kc = r*16 + j for conv; kc = 48 for center. B[k][n]: n = lane&15, k = c = 8*(lane>>4)+i.
__global__ __launch_bounds__(256) void prepack_kernel(
    const float* __restrict__ kern, const float* __restrict__ ckern,
    unsigned short* __restrict__ bpack)
{
  int tid = blockIdx.x*256 + threadIdx.x;
  if (tid >= 4*BPACK_Q_USHORT) return;
  int fq  = tid / BPACK_Q_USHORT;
  int rem = tid - fq*BPACK_Q_USHORT;
  int kc  = rem >> 9;
  int e   = rem & 511;
  int l   = e >> 3, i = e & 7;
  int f   = fq*16 + (l & 15);
  int c   = ((l >> 4) << 3) + i;
  float v;
  if (kc < 48) {
    int r = kc >> 4, j = kc & 15;
    v = kern[((r*16 + j)*32 + c)*64 + f];
  } else {
    v = ckern[c*64 + f];
  }
  bpack[tid] = f2bf(v);
}

// ---- staging macros (10 steps: step s covers vert v = s>>1, dir dd = (s&1)*8 + rsl) ----
// em -> row index immediately (10 regs)
#define EMLOAD(dst, gg, rr)                                                    \
  {                                                                            \
    const char* ebp = (const char*)em + (((size_t)(gg)*5)*48 + (rr)*16 + rsl)*8;\
    _Pragma("unroll")                                                          \
    for (int s = 0; s < 10; ++s) {                                             \
      const int2 e = *(const int2*)(ebp + (s >> 1)*384 + (s & 1)*64);          \
      dst[s] = e.y + (e.x ? NVERT : 0);                                        \
    }                                                                          \
  }

// ISSUE y row loads into float4 regs (stay in flight across the JLOOP — T14)
#define YISSUE(dst, rb)                                                        \
  {                                                                            \
    _Pragma("unroll")                                                          \
    for (int s = 0; s < 10; ++s)                                               \
      dst[s] = *(const float4*)((const char*)y + (size_t)rb[s]*128 + cp*16);   \
  }

// pack + LDS-write AFTER the JLOOP (write-late half of T14)
#define WRITEPK(parX, src)                                                     \
  {                                                                            \
    char* wp = swb + (parX)*5120;                                              \
    _Pragma("unroll")                                                          \
    for (int s = 0; s < 10; ++s)                                               \
      *(uint2*)(wp + (s >> 1)*1024 + (s & 1)*512) = pack4(src[s]);             \
  }

#define AREAD(parX)                                                            \
  {                                                                            \
    const char* ap = arb + (parX)*5120;                                        \
    a0 = *(const bf16x8*)(ap);                                                 \
    a1 = *(const bf16x8*)(ap + 1024);                                          \
    a2 = *(const bf16x8*)(ap + 2048);                                          \
    a3 = *(const bf16x8*)(ap + 3072);                                          \
    a4 = *(const bf16x8*)(ap + 4096);                                          \
  }

// One r-pass: B fragment per j (canonical lane*16 read, 0 conflicts), 5 MFMA per
// B-read (one per vertex), A rotated in-register over the direction dim (DPP).
#define JLOOP(rr)                                                              \
  {                                                                            \
    const char* bp = bbase + (size_t)(rr)*16384;                               \
    __builtin_amdgcn_s_setprio(1);                                             \
    _Pragma("unroll")                                                          \
    for (int j = 0; j < 16; ++j) {                                             \
      const bf16x8 b = *(const bf16x8*)(bp + (size_t)j*1024);                  \
      acc0 = __builtin_amdgcn_mfma_f32_16x16x32_bf16(a0, b, acc0, 0, 0, 0);    \
      acc1 = __builtin_amdgcn_mfma_f32_16x16x32_bf16(a1, b, acc1, 0, 0, 0);    \
      acc2 = __builtin_amdgcn_mfma_f32_16x16x32_bf16(a2, b, acc2, 0, 0, 0);    \
      acc3 = __builtin_amdgcn_mfma_f32_16x16x32_bf16(a3, b, acc3, 0, 0, 0);    \
      acc4 = __builtin_amdgcn_mfma_f32_16x16x32_bf16(a4, b, acc4, 0, 0, 0);    \
      if (j < 15) { a0 = rot16(a0); a1 = rot16(a1); a2 = rot16(a2);            \
                    a3 = rot16(a3); a4 = rot16(a4); }                          \
    }                                                                          \
    __builtin_amdgcn_s_setprio(0);                                             \
  }

// NOTE: 512-thread block => 8 waves co-resident on one CU => 2 waves/SIMD floor
// => ~128 arch-VGPR budget/wave (unified file). The kernel is REDESIGNED to fit:
// one rowi array (not two) and T14 issue-early/write-late staging (no packed sv
// array live across MFMA loops). Peak live ~105-118 regs.
__global__ __launch_bounds__(512, 1) void conv_kernel(
    const float* __restrict__ y,
    const int*   __restrict__ em,     // exp_map int pairs (b,v), flat (u*48 + r*16+dd)
    const float* __restrict__ bias,
    const unsigned short* __restrict__ bpack,
    float* __restrict__ out)
{
  extern __shared__ __align__(16) char smem[];
  const int fq  = blockIdx.x & 3;     // which 16-wide f quarter
  const int bl  = blockIdx.x >> 2;    // 0..63
  const int tid = threadIdx.x;
  const int w   = tid >> 6;           // wave 0..7
  const int l   = tid & 63;

  // ---- stage this f-quarter's B fragments into LDS (once per block) ----
  {
    const uint4* src = (const uint4*)(bpack + (size_t)fq * BPACK_Q_USHORT);
    uint4* dst = (uint4*)smem;
    for (int idx = tid; idx < LDS_B16/16; idx += 512) dst[idx] = src[idx];
  }
  __syncthreads();   // the ONLY barrier — B-pack is read-only afterwards

  const char* bbase = smem + (size_t)l * 16;     // canonical fragment read
  char* const patch = smem + LDS_B16 + w*WPATCH; // PRIVATE: 2 slots x 5 verts + center
  const int d  = l & 15;              // A-operand: direction row (m)
  const int g4 = l >> 4;              // A/B operand: k-group selector
  const float biasv = bias[fq*16 + d];

  // staging lane roles: 8 lanes x 16B cover a 128B fp32 row
  const int rsl = l >> 3, cp = l & 7;
  char* const swb = patch + rsl*64 + cp*8;       // + par*5120 + v*1024 + (s&1)*512
  const char* const arb = patch + d*64 + g4*16;  // + par*5120 + v*1024
  char* const cwb = patch + 2*5120 + rsl*64 + cp*8;   // center write (lanes 0..39)
  const char* const crb = patch + 2*5120 + g4*16;     // center read (+v*64, bcast over d)

  const int wid = bl*8 + w;           // wave-task id within this f-quarter: 0..511

  int rowi[10];
  float4 yv[10];

  // ---- prologue: stage group wid's r=0 into slot0; rowi <- em(r=1) ----
  EMLOAD(rowi, wid, 0)
  YISSUE(yv, rowi)
  WRITEPK(0, yv)
  EMLOAD(rowi, wid, 1)

  int par = 0;
  for (int g = wid; g < NGRP5; g += 512) {
    const int gn = g + 512;
    const int gp = (gn < NGRP5) ? gn : g;   // clamped prefetch (results unused on last iter)

    f32x4 acc0, acc1, acc2, acc3, acc4;
#pragma unroll
    for (int k = 0; k < 4; ++k) { acc0[k]=0.f; acc1[k]=0.f; acc2[k]=0.f; acc3[k]=0.f; acc4[k]=0.f; }

    bf16x8 a0, a1, a2, a3, a4;

    // ---- phase 0: compute r=0 from slot par; r=1 loads fly over JLOOP(0) ----
    AREAD(par)
    YISSUE(yv, rowi)       // r=1 rows (em loaded last phase 2 / prologue)
    // center rows for g -> LDS (lanes 0..39; 5 rows x 64B bf16), read after JLOOP(0)
    if (l < 40)
      *(uint2*)(cwb) = pack4(*(const float4*)((const char*)y + (size_t)(g*5 + rsl)*128 + cp*16));
    EMLOAD(rowi, g, 2)     // em for r=2 (hidden under JLOOP(0))
    JLOOP(0)
    WRITEPK(par^1, yv)     // r=1 -> slot par^1 (read at phase 1 AREAD)

    // ---- center term: A broadcast over d from LDS (transient frags, 5 MFMAs) ----
    {
      const bf16x8 bc = *(const bf16x8*)(bbase + 48*1024);
      acc0 = __builtin_amdgcn_mfma_f32_16x16x32_bf16(*(const bf16x8*)(crb),        bc, acc0, 0, 0, 0);
      acc1 = __builtin_amdgcn_mfma_f32_16x16x32_bf16(*(const bf16x8*)(crb + 64),   bc, acc1, 0, 0, 0);
      acc2 = __builtin_amdgcn_mfma_f32_16x16x32_bf16(*(const bf16x8*)(crb + 128),  bc, acc2, 0, 0, 0);
      acc3 = __builtin_amdgcn_mfma_f32_16x16x32_bf16(*(const bf16x8*)(crb + 192),  bc, acc3, 0, 0, 0);
      acc4 = __builtin_amdgcn_mfma_f32_16x16x32_bf16(*(const bf16x8*)(crb + 256),  bc, acc4, 0, 0, 0);
    }

    // ---- phase 1: compute r=1 from slot par^1; r=2 loads fly over JLOOP(1) ----
    AREAD(par^1)
    YISSUE(yv, rowi)       // r=2 rows
    EMLOAD(rowi, gp, 0)    // em for next iter r=0
    JLOOP(1)
    WRITEPK(par, yv)       // r=2 -> slot par (read at phase 2 AREAD)

    // ---- phase 2: compute r=2 from slot par; next r=0 loads fly over JLOOP(2) ----
    AREAD(par)
    YISSUE(yv, rowi)       // next iter r=0 rows
    EMLOAD(rowi, gp, 1)    // em for next iter r=1
    JLOOP(2)
    WRITEPK(par^1, yv)     // next r=0 -> slot par^1 (read at next iter phase 0, par flipped)

    // ---- epilogue: C/D 16x16 (m89): col = lane&15 = f, row = (lane>>4)*4+reg = dd.
    // max over dd = max over 4 regs then lane-groups (xor 16, 32); +bias, relu.
    {
      float m0 = fmaxf(fmaxf(acc0[0], acc0[1]), fmaxf(acc0[2], acc0[3]));
      float m1 = fmaxf(fmaxf(acc1[0], acc1[1]), fmaxf(acc1[2], acc1[3]));
      float m2 = fmaxf(fmaxf(acc2[0], acc2[1]), fmaxf(acc2[2], acc2[3]));
      float m3 = fmaxf(fmaxf(acc3[0], acc3[1]), fmaxf(acc3[2], acc3[3]));
      float m4 = fmaxf(fmaxf(acc4[0], acc4[1]), fmaxf(acc4[2], acc4[3]));
      m0 = fmaxf(m0, __shfl_xor(m0, 16)); m0 = fmaxf(m0, __shfl_xor(m0, 32));
      m1 = fmaxf(m1, __shfl_xor(m1, 16)); m1 = fmaxf(m1, __shfl_xor(m1, 32));
      m2 = fmaxf(m2, __shfl_xor(m2, 16)); m2 = fmaxf(m2, __shfl_xor(m2, 32));
      m3 = fmaxf(m3, __shfl_xor(m3, 16)); m3 = fmaxf(m3, __shfl_xor(m3, 32));
      m4 = fmaxf(m4, __shfl_xor(m4, 16)); m4 = fmaxf(m4, __shfl_xor(m4, 32));
      // verts g*5+0..3 via g4-select (all 64 lanes store distinct (vert, f))
      const float sel = (g4 == 0) ? m0 : (g4 == 1) ? m1 : (g4 == 2) ? m2 : m3;
      out[(size_t)(g*5 + g4)*64 + fq*16 + d] = fmaxf(sel + biasv, 0.f);
      // vert g*5+4: lanes 0..15
      if (l < 16)
        out[(size_t)(g*5 + 4)*64 + fq*16 + l] = fmaxf(m4 + biasv, 0.f);
    }

    par ^= 1;
  }
}

extern "C" void kernel_launch(void* const* d_in, const int* in_sizes, int n_in,
                              void* d_out, int out_size, void* d_ws, size_t ws_size,
                              hipStream_t stream) {
  const float* y     = (const float*)d_in[0];
  const int*   em    = (const int*)  d_in[1];
  const float* kern  = (const float*)d_in[2];
  const float* ckern = (const float*)d_in[3];
  const float* bias  = (const float*)d_in[4];
  float* out = (float*)d_out;
  unsigned short* bpack = (unsigned short*)d_ws;   // 200704 bytes used

  // opt in to >64KB dynamic LDS (host-side, graph-capture safe — verified many rounds)
  hipFuncSetAttribute(reinterpret_cast<const void*>(conv_kernel),
                      hipFuncAttributeMaxDynamicSharedMemorySize, LDS_TOT);

  prepack_kernel<<<(4*BPACK_Q_USHORT + 255)/256, 256, 0, stream>>>(kern, ckern, bpack);
  conv_kernel<<<256, 512, LDS_TOT, stream>>>(y, em, bias, bpack, out);
}

// Round 8
// 652.627 us; speedup vs baseline: 2.4763x; 2.4763x over previous
//
#include <hip/hip_runtime.h>
#include <hip/hip_bf16.h>
#include <stdint.h>

// Problem constants (B=2, NV=25000, C=32, NR=3, ND=16, F=64)
#define NVERT 25000      // vertices per batch
#define NGRP4 12500      // groups of 4 vertices (2 pairs)

typedef __bf16  bf16x8 __attribute__((ext_vector_type(8)));
typedef float   f32x16 __attribute__((ext_vector_type(16)));

// ---- 32x32x16 design: f-half (n=32) B-pack, 98 chunks in global bpack
// (96 conv (r,ch,j) + 2 center). LDS holds 90 conv chunks (j=0..14 per (r,ch));
// the 6 j=15 chunks + 2 center chunks are read from L2-resident bpack directly.
#define BPACK_HALF_USHORT (98*512)   // ushorts per f-half pack
#define NLDSC   90
#define LDS_B   (NLDSC*1024)         // 92160 B of B-fragments in LDS
#define SLOT    4096                 // per-parity patch: 4 verts x 16 rows x 64 B
#define WPATCH  (2*SLOT)             // 8192 B per wave (double-buffered)
#define LDS_TOT (LDS_B + 8*WPATCH)   // 157696 <= 163840; 1 block/CU, 2 waves/SIMD

__device__ __forceinline__ uint2 pack4(float4 v) {
  union { __hip_bfloat162 h; unsigned u; } a, b;
  a.h = __float22bfloat162_rn(float2{v.x, v.y});
  b.h = __float22bfloat162_rn(float2{v.z, v.w});
  return uint2{a.u, b.u};
}

__device__ __forceinline__ bf16x8 mkfrag(float4 a, float4 b) {
  union { bf16x8 v; uint2 u[2]; } t;
  t.u[0] = pack4(a);   // elems 0..3
  t.u[1] = pack4(b);   // elems 4..7
  return t.v;
}

__device__ __forceinline__ unsigned short f2bf(float f) {
  unsigned int u = __float_as_uint(f);
  u += 0x7FFFu + ((u >> 16) & 1u);   // round-to-nearest-even
  return (unsigned short)(u >> 16);
}

// lane-rotate within 16-lane rows (row_ror:15): dst[i] = src[(i+1)&15] — harness-verified
__device__ __forceinline__ bf16x8 rot16(bf16x8 x) {
  union { bf16x8 v; int i[4]; } u;
  u.v = x;
#pragma unroll
  for (int k = 0; k < 4; ++k)
    u.i[k] = __builtin_amdgcn_update_dpp(u.i[k], u.i[k], 0x12F, 0xF, 0xF, false);
  return u.v;
}

// Pack kernel (3,16,32,64) + center_kernel (32,64) into 32x32x16 MFMA B-fragment order.
// Layout: bpack[fh(2)][kc(98)][lane(64)][i(8)] ushort. kc = (r*2+ch)*16 + j conv;
// kc = 96+ch center. B[k][n]: n = lane&31 (f within half), k = 8*(lane>>5)+i, c = ch*16+k.
// (R0-verified layout, verbatim.)
__global__ __launch_bounds__(256) void prepack_kernel(
    const float* __restrict__ kern, const float* __restrict__ ckern,
    unsigned short* __restrict__ bpack)
{
  int tid = blockIdx.x*256 + threadIdx.x;
  if (tid >= 2*BPACK_HALF_USHORT) return;
  int fh  = tid / BPACK_HALF_USHORT;
  int rem = tid - fh*BPACK_HALF_USHORT;
  int kc  = rem >> 9;
  int e   = rem & 511;
  int l   = e >> 3, i = e & 7;
  int f   = fh*32 + (l & 31);
  int kk  = ((l >> 5) << 3) + i;
  float v;
  if (kc < 96) {
    int r = kc >> 5, ch = (kc >> 4) & 1, j = kc & 15;
    int c = ch*16 + kk;
    v = kern[((r*16 + j)*32 + c)*64 + f];
  } else {
    int c = (kc - 96)*16 + kk;
    v = ckern[c*64 + f];
  }
  bpack[tid] = f2bf(v);
}

// ---- staging macros (8 steps: step it covers vert v = it>>1, dir dd = (it&1)*8 + rsl)
#define EMLOAD(dst, gg, rr)                                                    \
  {                                                                            \
    const char* ebp = (const char*)em + (size_t)(gg)*1536 + (rr)*128 + rsl*8;  \
    _Pragma("unroll")                                                          \
    for (int it = 0; it < 8; ++it) {                                           \
      const int2 e = *(const int2*)(ebp + (it >> 1)*384 + (it & 1)*64);        \
      dst[it] = e.y + (e.x ? NVERT : 0);                                       \
    }                                                                          \
  }

// load float4 + pack to uint2 ON ARRIVAL (16 regs live — R2's no-spill discipline)
#define YSTAGE(dst, rb)                                                        \
  {                                                                            \
    _Pragma("unroll")                                                          \
    for (int it = 0; it < 8; ++it)                                             \
      dst[it] = pack4(*(const float4*)((const char*)y + (size_t)rb[it]*128 + cp*16));\
  }

#define WRITE(parX, src)                                                       \
  {                                                                            \
    char* wp = swb + (parX)*SLOT;                                              \
    _Pragma("unroll")                                                          \
    for (int it = 0; it < 8; ++it)                                             \
      *(uint2*)(wp + (it >> 1)*1024 + (it & 1)*512) = src[it];                 \
  }

// A fragments: pair0 verts {0,1} (a00 c-lo, a01 c-hi), pair1 verts {2,3}.
// addr = v*1024 + dd*64 + hi*16 (+32 for c-hi). ~4-way bank aliasing on the 64B
// row stride — 12 reads/iter, bounded cost vs 96 conflict-free B-reads.
#define AREAD(parX)                                                            \
  {                                                                            \
    const char* ap = arb + (parX)*SLOT;                                        \
    a00 = *(const bf16x8*)(ap);                                                \
    a01 = *(const bf16x8*)(ap + 32);                                           \
    a10 = *(const bf16x8*)(ap + 2048);                                         \
    a11 = *(const bf16x8*)(ap + 2080);                                         \
  }

// One r-pass: per j, 2 B-frags (canonical lane*16 contiguous read, 0 conflicts)
// feed 4 MFMA (2 pairs x 2 c-halves); 4 frag rotations (16 dpp). j=15's B comes
// from global bpack (L2-hot), prefetched at loop entry — 15 j's of latency cover.
#define JLOOP(rr)                                                              \
  {                                                                            \
    const char* bpl = bbase + (rr)*30720;                                      \
    const bf16x8 gb0 = *(const bf16x8*)(bpg + ((rr)*32 + 15)*1024);            \
    const bf16x8 gb1 = *(const bf16x8*)(bpg + ((rr)*32 + 31)*1024);            \
    __builtin_amdgcn_s_setprio(1);                                             \
    _Pragma("unroll")                                                          \
    for (int j = 0; j < 15; ++j) {                                             \
      const bf16x8 b0 = *(const bf16x8*)(bpl + j*1024);                        \
      const bf16x8 b1 = *(const bf16x8*)(bpl + j*1024 + 15360);                \
      acc0 = __builtin_amdgcn_mfma_f32_32x32x16_bf16(a00, b0, acc0, 0, 0, 0);  \
      acc1 = __builtin_amdgcn_mfma_f32_32x32x16_bf16(a10, b0, acc1, 0, 0, 0);  \
      acc0 = __builtin_amdgcn_mfma_f32_32x32x16_bf16(a01, b1, acc0, 0, 0, 0);  \
      acc1 = __builtin_amdgcn_mfma_f32_32x32x16_bf16(a11, b1, acc1, 0, 0, 0);  \
      a00 = rot16(a00); a01 = rot16(a01); a10 = rot16(a10); a11 = rot16(a11);  \
    }                                                                          \
    acc0 = __builtin_amdgcn_mfma_f32_32x32x16_bf16(a00, gb0, acc0, 0, 0, 0);   \
    acc1 = __builtin_amdgcn_mfma_f32_32x32x16_bf16(a10, gb0, acc1, 0, 0, 0);   \
    acc0 = __builtin_amdgcn_mfma_f32_32x32x16_bf16(a01, gb1, acc0, 0, 0, 0);   \
    acc1 = __builtin_amdgcn_mfma_f32_32x32x16_bf16(a11, gb1, acc1, 0, 0, 0);   \
    __builtin_amdgcn_s_setprio(0);                                             \
  }

__global__ __launch_bounds__(512, 1) void conv_kernel(
    const float* __restrict__ y,
    const int*   __restrict__ em,     // exp_map int pairs (b,v), flat (u*48 + r*16+dd)
    const float* __restrict__ bias,
    const unsigned short* __restrict__ bpack,
    float* __restrict__ out)
{
  extern __shared__ __align__(16) char smem[];
  const int fh  = blockIdx.x & 1;     // which 32-wide f half
  const int bl  = blockIdx.x >> 1;    // 0..127
  const int tid = threadIdx.x;
  const int w   = tid >> 6;           // wave 0..7
  const int l   = tid & 63;

  // ---- stage 90 conv B-chunks into LDS (skip j=15 chunks), once per block ----
  {
    const uint4* src = (const uint4*)(bpack + (size_t)fh * BPACK_HALF_USHORT);
    uint4* dst = (uint4*)smem;
    for (int idx = tid; idx < NLDSC*64; idx += 512) {
      const int c90 = idx >> 6, within = idx & 63;
      const int blk = c90 / 15, jj = c90 - blk*15;
      dst[idx] = src[(blk*16 + jj)*64 + within];
    }
  }
  __syncthreads();   // the ONLY barrier — B-pack is read-only afterwards

  const char* bbase = smem + (size_t)l * 16;     // canonical fragment read
  const char* bpg = (const char*)bpack + (size_t)fh*(BPACK_HALF_USHORT*2) + (size_t)l*16;
  char* const patch = smem + LDS_B + w*WPATCH;   // PRIVATE: 2 parity slots x 4 verts
  const int hi = l >> 5;              // k-half selector
  const float biasv = bias[fh*32 + (l & 31)];

  // center B fragments (chunks 96,97) live in 8 VGPRs, loaded once from global
  const bf16x8 bc0 = *(const bf16x8*)(bpg + 96*1024);
  const bf16x8 bc1 = *(const bf16x8*)(bpg + 97*1024);

  // staging lane roles: 8 lanes x 16B cover a 128B fp32 row
  const int rsl = l >> 3, cp = l & 7;
  char* const swb = patch + rsl*64 + cp*8;
  const char* const arb = patch + ((l >> 4) & 1)*1024 + (l & 15)*64 + hi*16;

  const int wid = bl*8 + w;           // wave-task id within this f-half: 0..1023

  int rowi[8];
  uint2 sv[8];

  // ---- prologue: stage group wid's r=0 into slot0; rowi <- em(r=1) ----
  EMLOAD(rowi, wid, 0)
  YSTAGE(sv, rowi)
  WRITE(0, sv)
  EMLOAD(rowi, wid, 1)

  int par = 0;
  for (int g = wid; g < NGRP4; g += 1024) {
    const int gn = g + 1024;
    const int gp = (gn < NGRP4) ? gn : g;   // clamped prefetch (unused on last iter)

    f32x16 acc0, acc1;
#pragma unroll
    for (int k = 0; k < 16; ++k) { acc0[k] = 0.f; acc1[k] = 0.f; }

    bf16x8 a00, a01, a10, a11;

    // ---- phase 0: compute r=0 from slot par; stage r=1 -> slot par^1 ----
    AREAD(par)
    YSTAGE(sv, rowi)       // r=1 rows (em loaded last phase 2 / prologue)
    EMLOAD(rowi, g, 2)     // em for r=2 (hidden under JLOOP(0))
    JLOOP(0)
    WRITE(par^1, sv)

    // ---- center term: direct global reads (y L2/L3-hot), in-reg frags, 4 MFMA ----
    {
      const char* cb = (const char*)y + (size_t)g*512 + ((l >> 4) & 1)*128 + hi*32;
      const float4 x0 = *(const float4*)(cb);
      const float4 x1 = *(const float4*)(cb + 16);
      const float4 x2 = *(const float4*)(cb + 64);
      const float4 x3 = *(const float4*)(cb + 80);
      const float4 x4 = *(const float4*)(cb + 256);
      const float4 x5 = *(const float4*)(cb + 272);
      const float4 x6 = *(const float4*)(cb + 320);
      const float4 x7 = *(const float4*)(cb + 336);
      acc0 = __builtin_amdgcn_mfma_f32_32x32x16_bf16(mkfrag(x0, x1), bc0, acc0, 0, 0, 0);
      acc0 = __builtin_amdgcn_mfma_f32_32x32x16_bf16(mkfrag(x2, x3), bc1, acc0, 0, 0, 0);
      acc1 = __builtin_amdgcn_mfma_f32_32x32x16_bf16(mkfrag(x4, x5), bc0, acc1, 0, 0, 0);
      acc1 = __builtin_amdgcn_mfma_f32_32x32x16_bf16(mkfrag(x6, x7), bc1, acc1, 0, 0, 0);
    }

    // ---- phase 1: compute r=1 from slot par^1; stage r=2 -> slot par ----
    AREAD(par^1)
    YSTAGE(sv, rowi)       // r=2 rows
    EMLOAD(rowi, gp, 0)    // em for next iter r=0
    JLOOP(1)
    WRITE(par, sv)

    // ---- phase 2: compute r=2 from slot par; stage next r=0 -> slot par^1 ----
    AREAD(par)
    YSTAGE(sv, rowi)       // next iter r=0 rows
    EMLOAD(rowi, gp, 1)    // em for next iter r=1
    JLOOP(2)
    WRITE(par^1, sv)

    // ---- epilogue (R1-verified): C/D 32x32 (m74/m101): n = lane&31,
    // m = (reg&3)+8*(reg>>2)+4*(lane>>5); regs 0..7 = vert lo, 8..15 = vert hi.
    {
      float m0 = acc0[0], m1 = acc0[8];
#pragma unroll
      for (int k = 1; k < 8; ++k) { m0 = fmaxf(m0, acc0[k]); m1 = fmaxf(m1, acc0[8+k]); }
      m0 = fmaxf(m0, __shfl_xor(m0, 32, 64));
      m1 = fmaxf(m1, __shfl_xor(m1, 32, 64));
      float v = (hi ? m1 : m0) + biasv;
      out[(size_t)(g*4 + hi)*64 + fh*32 + (l & 31)] = fmaxf(v, 0.f);
    }
    {
      float m0 = acc1[0], m1 = acc1[8];
#pragma unroll
      for (int k = 1; k < 8; ++k) { m0 = fmaxf(m0, acc1[k]); m1 = fmaxf(m1, acc1[8+k]); }
      m0 = fmaxf(m0, __shfl_xor(m0, 32, 64));
      m1 = fmaxf(m1, __shfl_xor(m1, 32, 64));
      float v = (hi ? m1 : m0) + biasv;
      out[(size_t)(g*4 + 2 + hi)*64 + fh*32 + (l & 31)] = fmaxf(v, 0.f);
    }

    par ^= 1;
  }
}

extern "C" void kernel_launch(void* const* d_in, const int* in_sizes, int n_in,
                              void* d_out, int out_size, void* d_ws, size_t ws_size,
                              hipStream_t stream) {
  const float* y     = (const float*)d_in[0];
  const int*   em    = (const int*)  d_in[1];
  const float* kern  = (const float*)d_in[2];
  const float* ckern = (const float*)d_in[3];
  const float* bias  = (const float*)d_in[4];
  float* out = (float*)d_out;
  unsigned short* bpack = (unsigned short*)d_ws;   // 200704 bytes used

  // opt in to >64KB dynamic LDS (host-side, graph-capture safe — verified many rounds)
  hipFuncSetAttribute(reinterpret_cast<const void*>(conv_kernel),
                      hipFuncAttributeMaxDynamicSharedMemorySize, LDS_TOT);

  prepack_kernel<<<(2*BPACK_HALF_USHORT + 255)/256, 256, 0, stream>>>(kern, ckern, bpack);
  conv_kernel<<<256, 512, LDS_TOT, stream>>>(y, em, bias, bpack, out);
}

// Round 9
// 483.581 us; speedup vs baseline: 3.3419x; 1.3496x over previous
//
#include <hip/hip_runtime.h>
#include <hip/hip_bf16.h>
#include <stdint.h>

// Problem constants (B=2, NV=25000, C=32, NR=3, ND=16, F=64)
#define NVERT 25000      // vertices per batch
#define NGRP4 12500      // groups of 4 vertices (2 pairs)

typedef __bf16  bf16x8 __attribute__((ext_vector_type(8)));
typedef float   f32x16 __attribute__((ext_vector_type(16)));

// ---- 32x32x16 design: f-half (n=32) B-pack, 98 chunks in global bpack
// (96 conv (r,ch,j) + 2 center). LDS holds 90 conv chunks (j=0..14 per (r,ch));
// the 6 j=15 chunks + 2 center chunks are read from L2-resident bpack directly.
#define BPACK_HALF_USHORT (98*512)   // ushorts per f-half pack
#define NLDSC   90
#define LDS_B   (NLDSC*1024)         // 92160 B of B-fragments in LDS
#define SLOT    4096                 // per-parity patch: 4 verts x 16 rows x 64 B
#define WPATCH  (2*SLOT)             // 8192 B per wave (double-buffered)
#define LDS_TOT (LDS_B + 8*WPATCH)   // 157696 <= 163840; 1 block/CU, 2 waves/SIMD

__device__ __forceinline__ uint2 pack4(float4 v) {
  union { __hip_bfloat162 h; unsigned u; } a, b;
  a.h = __float22bfloat162_rn(float2{v.x, v.y});
  b.h = __float22bfloat162_rn(float2{v.z, v.w});
  return uint2{a.u, b.u};
}

__device__ __forceinline__ bf16x8 mkfrag(float4 a, float4 b) {
  union { bf16x8 v; uint2 u[2]; } t;
  t.u[0] = pack4(a);   // elems 0..3
  t.u[1] = pack4(b);   // elems 4..7
  return t.v;
}

__device__ __forceinline__ unsigned short f2bf(float f) {
  unsigned int u = __float_as_uint(f);
  u += 0x7FFFu + ((u >> 16) & 1u);   // round-to-nearest-even
  return (unsigned short)(u >> 16);
}

// lane-rotate within 16-lane rows (row_ror:15): dst[i] = src[(i+1)&15] — harness-verified
__device__ __forceinline__ bf16x8 rot16(bf16x8 x) {
  union { bf16x8 v; int i[4]; } u;
  u.v = x;
#pragma unroll
  for (int k = 0; k < 4; ++k)
    u.i[k] = __builtin_amdgcn_update_dpp(u.i[k], u.i[k], 0x12F, 0xF, 0xF, false);
  return u.v;
}

// Pack kernel (3,16,32,64) + center_kernel (32,64) into 32x32x16 MFMA B-fragment order.
// Layout: bpack[fh(2)][kc(98)][lane(64)][i(8)] ushort. kc = (r*2+ch)*16 + j conv;
// kc = 96+ch center. B[k][n]: n = lane&31 (f within half), k = 8*(lane>>5)+i, c = ch*16+k.
// (R0-verified layout, verbatim.)
__global__ __launch_bounds__(256) void prepack_kernel(
    const float* __restrict__ kern, const float* __restrict__ ckern,
    unsigned short* __restrict__ bpack)
{
  int tid = blockIdx.x*256 + threadIdx.x;
  if (tid >= 2*BPACK_HALF_USHORT) return;
  int fh  = tid / BPACK_HALF_USHORT;
  int rem = tid - fh*BPACK_HALF_USHORT;
  int kc  = rem >> 9;
  int e   = rem & 511;
  int l   = e >> 3, i = e & 7;
  int f   = fh*32 + (l & 31);
  int kk  = ((l >> 5) << 3) + i;
  float v;
  if (kc < 96) {
    int r = kc >> 5, ch = (kc >> 4) & 1, j = kc & 15;
    int c = ch*16 + kk;
    v = kern[((r*16 + j)*32 + c)*64 + f];
  } else {
    int c = (kc - 96)*16 + kk;
    v = ckern[c*64 + f];
  }
  bpack[tid] = f2bf(v);
}

// ---- staging macros (8 steps: step it covers vert v = it>>1, dir dd = (it&1)*8 + rsl)
#define EMLOAD(dst, gg, rr)                                                    \
  {                                                                            \
    const char* ebp = (const char*)em + (size_t)(gg)*1536 + (rr)*128 + rsl*8;  \
    _Pragma("unroll")                                                          \
    for (int it = 0; it < 8; ++it) {                                           \
      const int2 e = *(const int2*)(ebp + (it >> 1)*384 + (it & 1)*64);        \
      dst[it] = e.y + (e.x ? NVERT : 0);                                       \
    }                                                                          \
  }

// load float4 + pack to uint2 ON ARRIVAL (16 regs live — R2's no-spill discipline)
#define YSTAGE(dst, rb)                                                        \
  {                                                                            \
    _Pragma("unroll")                                                          \
    for (int it = 0; it < 8; ++it)                                             \
      dst[it] = pack4(*(const float4*)((const char*)y + (size_t)rb[it]*128 + cp*16));\
  }

#define WRITE(parX, src)                                                       \
  {                                                                            \
    char* wp = swb + (parX)*SLOT;                                              \
    _Pragma("unroll")                                                          \
    for (int it = 0; it < 8; ++it)                                             \
      *(uint2*)(wp + (it >> 1)*1024 + (it & 1)*512) = src[it];                 \
  }

// A fragments: pair0 verts {0,1} (a00 c-lo, a01 c-hi), pair1 verts {2,3}.
#define AREAD(parX)                                                            \
  {                                                                            \
    const char* ap = arb + (parX)*SLOT;                                        \
    a00 = *(const bf16x8*)(ap);                                                \
    a01 = *(const bf16x8*)(ap + 32);                                           \
    a10 = *(const bf16x8*)(ap + 2048);                                         \
    a11 = *(const bf16x8*)(ap + 2080);                                         \
  }

// One r-pass: per j, 2 B-frags (canonical lane*16 contiguous read, 0 conflicts)
// feed 4 MFMA (2 pairs x 2 c-halves); 4 frag rotations (16 dpp). j=15's B comes
// from global bpack (L2-hot), prefetched at loop entry — 15 j's of latency cover.
// sched_barrier(0) every 4 j's caps ds_read hoisting (<=8 reads ahead = 64 regs)
// so the unrolled loop cannot blow past the 2-wave/SIMD register budget.
#define JLOOP(rr)                                                              \
  {                                                                            \
    const char* bpl = bbase + (rr)*30720;                                      \
    const bf16x8 gb0 = *(const bf16x8*)(bpg + ((rr)*32 + 15)*1024);            \
    const bf16x8 gb1 = *(const bf16x8*)(bpg + ((rr)*32 + 31)*1024);            \
    __builtin_amdgcn_s_setprio(1);                                             \
    _Pragma("unroll")                                                          \
    for (int j = 0; j < 15; ++j) {                                             \
      const bf16x8 b0 = *(const bf16x8*)(bpl + j*1024);                        \
      const bf16x8 b1 = *(const bf16x8*)(bpl + j*1024 + 15360);                \
      acc0 = __builtin_amdgcn_mfma_f32_32x32x16_bf16(a00, b0, acc0, 0, 0, 0);  \
      acc1 = __builtin_amdgcn_mfma_f32_32x32x16_bf16(a10, b0, acc1, 0, 0, 0);  \
      acc0 = __builtin_amdgcn_mfma_f32_32x32x16_bf16(a01, b1, acc0, 0, 0, 0);  \
      acc1 = __builtin_amdgcn_mfma_f32_32x32x16_bf16(a11, b1, acc1, 0, 0, 0);  \
      a00 = rot16(a00); a01 = rot16(a01); a10 = rot16(a10); a11 = rot16(a11);  \
      if ((j & 3) == 3) __builtin_amdgcn_sched_barrier(0);                     \
    }                                                                          \
    acc0 = __builtin_amdgcn_mfma_f32_32x32x16_bf16(a00, gb0, acc0, 0, 0, 0);   \
    acc1 = __builtin_amdgcn_mfma_f32_32x32x16_bf16(a10, gb0, acc1, 0, 0, 0);   \
    acc0 = __builtin_amdgcn_mfma_f32_32x32x16_bf16(a01, gb1, acc0, 0, 0, 0);   \
    acc1 = __builtin_amdgcn_mfma_f32_32x32x16_bf16(a11, gb1, acc1, 0, 0, 0);   \
    __builtin_amdgcn_s_setprio(0);                                             \
  }

// Phase order is {AREAD -> YSTAGE -> EMLOAD -> WRITE} -> sched_barrier -> JLOOP:
// the staging registers (8 float4 in flight + 8 uint2 packed) are DEAD before the
// 64-MFMA loop starts. R8 had WRITE after JLOOP -> 48 regs live across the loop ->
// spills (WRITE_SIZE 1.4GB). WRITE-before-JLOOP is legal: the written slot's last
// reader was the AREAD two phases ago (same wave, program order).
__global__ __launch_bounds__(512, 1) void conv_kernel(
    const float* __restrict__ y,
    const int*   __restrict__ em,     // exp_map int pairs (b,v), flat (u*48 + r*16+dd)
    const float* __restrict__ bias,
    const unsigned short* __restrict__ bpack,
    float* __restrict__ out)
{
  extern __shared__ __align__(16) char smem[];
  const int fh  = blockIdx.x & 1;     // which 32-wide f half
  const int bl  = blockIdx.x >> 1;    // 0..127
  const int tid = threadIdx.x;
  const int w   = tid >> 6;           // wave 0..7
  const int l   = tid & 63;

  // ---- stage 90 conv B-chunks into LDS (skip j=15 chunks), once per block ----
  {
    const uint4* src = (const uint4*)(bpack + (size_t)fh * BPACK_HALF_USHORT);
    uint4* dst = (uint4*)smem;
    for (int idx = tid; idx < NLDSC*64; idx += 512) {
      const int c90 = idx >> 6, within = idx & 63;
      const int blk = c90 / 15, jj = c90 - blk*15;
      dst[idx] = src[(blk*16 + jj)*64 + within];
    }
  }
  __syncthreads();   // the ONLY barrier — B-pack is read-only afterwards

  const char* bbase = smem + (size_t)l * 16;     // canonical fragment read
  const char* bpg = (const char*)bpack + (size_t)fh*(BPACK_HALF_USHORT*2) + (size_t)l*16;
  char* const patch = smem + LDS_B + w*WPATCH;   // PRIVATE: 2 parity slots x 4 verts
  const int hi = l >> 5;              // k-half selector
  const float biasv = bias[fh*32 + (l & 31)];

  // center B fragments (chunks 96,97) live in 8 VGPRs, loaded once from global
  const bf16x8 bc0 = *(const bf16x8*)(bpg + 96*1024);
  const bf16x8 bc1 = *(const bf16x8*)(bpg + 97*1024);

  // staging lane roles: 8 lanes x 16B cover a 128B fp32 row
  const int rsl = l >> 3, cp = l & 7;
  char* const swb = patch + rsl*64 + cp*8;
  const char* const arb = patch + ((l >> 4) & 1)*1024 + (l & 15)*64 + hi*16;

  const int wid = bl*8 + w;           // wave-task id within this f-half: 0..1023

  int rowi[8];
  uint2 sv[8];

  // ---- prologue: stage group wid's r=0 into slot0; rowi <- em(r=1) ----
  EMLOAD(rowi, wid, 0)
  YSTAGE(sv, rowi)
  WRITE(0, sv)
  EMLOAD(rowi, wid, 1)

  int par = 0;
  for (int g = wid; g < NGRP4; g += 1024) {
    const int gn = g + 1024;
    const int gp = (gn < NGRP4) ? gn : g;   // clamped prefetch (unused on last iter)

    f32x16 acc0, acc1;
#pragma unroll
    for (int k = 0; k < 16; ++k) { acc0[k] = 0.f; acc1[k] = 0.f; }

    bf16x8 a00, a01, a10, a11;

    // ---- phase 0: read r=0 (slot par); stage r=1 -> slot par^1 BEFORE compute ----
    AREAD(par)
    YSTAGE(sv, rowi)       // r=1 rows (em loaded last phase 2 / prologue)
    EMLOAD(rowi, g, 2)     // em for r=2
    WRITE(par^1, sv)       // r=1 -> slot par^1 (read at phase 1)
    __builtin_amdgcn_sched_barrier(0);
    JLOOP(0)

    // ---- center term: direct global reads (y L2/L3-hot), in-reg frags, 4 MFMA ----
    {
      const char* cb = (const char*)y + (size_t)g*512 + ((l >> 4) & 1)*128 + hi*32;
      const float4 x0 = *(const float4*)(cb);
      const float4 x1 = *(const float4*)(cb + 16);
      const float4 x2 = *(const float4*)(cb + 64);
      const float4 x3 = *(const float4*)(cb + 80);
      const float4 x4 = *(const float4*)(cb + 256);
      const float4 x5 = *(const float4*)(cb + 272);
      const float4 x6 = *(const float4*)(cb + 320);
      const float4 x7 = *(const float4*)(cb + 336);
      acc0 = __builtin_amdgcn_mfma_f32_32x32x16_bf16(mkfrag(x0, x1), bc0, acc0, 0, 0, 0);
      acc0 = __builtin_amdgcn_mfma_f32_32x32x16_bf16(mkfrag(x2, x3), bc1, acc0, 0, 0, 0);
      acc1 = __builtin_amdgcn_mfma_f32_32x32x16_bf16(mkfrag(x4, x5), bc0, acc1, 0, 0, 0);
      acc1 = __builtin_amdgcn_mfma_f32_32x32x16_bf16(mkfrag(x6, x7), bc1, acc1, 0, 0, 0);
    }

    // ---- phase 1: read r=1 (slot par^1); stage r=2 -> slot par BEFORE compute ----
    AREAD(par^1)
    YSTAGE(sv, rowi)       // r=2 rows
    EMLOAD(rowi, gp, 0)    // em for next iter r=0
    WRITE(par, sv)         // r=2 -> slot par (read at phase 2)
    __builtin_amdgcn_sched_barrier(0);
    JLOOP(1)

    // ---- phase 2: read r=2 (slot par); stage next r=0 -> slot par^1 BEFORE compute ----
    AREAD(par)
    YSTAGE(sv, rowi)       // next iter r=0 rows
    EMLOAD(rowi, gp, 1)    // em for next iter r=1
    WRITE(par^1, sv)       // next r=0 -> slot par^1 (read at next iter phase 0, par flipped)
    __builtin_amdgcn_sched_barrier(0);
    JLOOP(2)

    // ---- epilogue (R1-verified): C/D 32x32 (m74/m101): n = lane&31,
    // m = (reg&3)+8*(reg>>2)+4*(lane>>5); regs 0..7 = vert lo, 8..15 = vert hi.
    {
      float m0 = acc0[0], m1 = acc0[8];
#pragma unroll
      for (int k = 1; k < 8; ++k) { m0 = fmaxf(m0, acc0[k]); m1 = fmaxf(m1, acc0[8+k]); }
      m0 = fmaxf(m0, __shfl_xor(m0, 32, 64));
      m1 = fmaxf(m1, __shfl_xor(m1, 32, 64));
      float v = (hi ? m1 : m0) + biasv;
      out[(size_t)(g*4 + hi)*64 + fh*32 + (l & 31)] = fmaxf(v, 0.f);
    }
    {
      float m0 = acc1[0], m1 = acc1[8];
#pragma unroll
      for (int k = 1; k < 8; ++k) { m0 = fmaxf(m0, acc1[k]); m1 = fmaxf(m1, acc1[8+k]); }
      m0 = fmaxf(m0, __shfl_xor(m0, 32, 64));
      m1 = fmaxf(m1, __shfl_xor(m1, 32, 64));
      float v = (hi ? m1 : m0) + biasv;
      out[(size_t)(g*4 + 2 + hi)*64 + fh*32 + (l & 31)] = fmaxf(v, 0.f);
    }

    par ^= 1;
  }
}

extern "C" void kernel_launch(void* const* d_in, const int* in_sizes, int n_in,
                              void* d_out, int out_size, void* d_ws, size_t ws_size,
                              hipStream_t stream) {
  const float* y     = (const float*)d_in[0];
  const int*   em    = (const int*)  d_in[1];
  const float* kern  = (const float*)d_in[2];
  const float* ckern = (const float*)d_in[3];
  const float* bias  = (const float*)d_in[4];
  float* out = (float*)d_out;
  unsigned short* bpack = (unsigned short*)d_ws;   // 200704 bytes used

  // opt in to >64KB dynamic LDS (host-side, graph-capture safe — verified many rounds)
  hipFuncSetAttribute(reinterpret_cast<const void*>(conv_kernel),
                      hipFuncAttributeMaxDynamicSharedMemorySize, LDS_TOT);

  prepack_kernel<<<(2*BPACK_HALF_USHORT + 255)/256, 256, 0, stream>>>(kern, ckern, bpack);
  conv_kernel<<<256, 512, LDS_TOT, stream>>>(y, em, bias, bpack, out);
}